// Round 3
// baseline (1216.355 us; speedup 1.0000x reference)
//
#include <hip/hip_runtime.h>
#include <math.h>

// Problem constants
#define HH 2048
#define EE 64
#define TOPK 8
#define NT 16384
#define BT 64            // tokens per WG (kernel1 tile: 64 tokens x 64 experts)
#define KC 32            // K chunk
#define LDH 36           // LDS row stride (floats): consecutive-row reads -> 2-way banks (free)
#define LS 68            // slog row stride (floats) in kernel2

// ---------------- Kernel 1: fp32 GEMM partial over a K-range ----------------
// grid (256, S); block 256. WG (m, s): tokens m*64..+64, experts 0..64,
// K in [s*kper, (s+1)*kper). Writes partials P[s][token][expert].
__global__ __launch_bounds__(256, 4) void gemm_part(
    const float* __restrict__ x,   // [NT, H]
    const float* __restrict__ w,   // [E, H]
    float* __restrict__ P,         // [S][NT, E]
    int kper)
{
    __shared__ float sh[2][BT * LDH];
    __shared__ float sw[2][BT * LDH];

    const int t  = threadIdx.x;
    const int tx = t & 15;         // expert base lane: experts tx+16j
    const int ty = t >> 4;         // token base lane:  tokens  ty+16i
    const int tok0 = blockIdx.x * BT;
    const int s    = blockIdx.y;
    const int k0   = s * kper;
    const int nch  = kper / KC;

    // staging role: thread t covers rows {t>>3, (t>>3)+32}, float4 col (t&7)*4
    const int srow = t >> 3;
    const int sc4  = (t & 7) * 4;

    float acc[4][4];
#pragma unroll
    for (int i = 0; i < 4; ++i)
#pragma unroll
        for (int j = 0; j < 4; ++j) acc[i][j] = 0.f;

    float4 px[2], pw[2];

    // ---- prologue: load chunk 0 ----
#pragma unroll
    for (int r = 0; r < 2; ++r) {
        const int row = srow + 32 * r;
        px[r] = *(const float4*)(x + (size_t)(tok0 + row) * HH + k0 + sc4);
        pw[r] = *(const float4*)(w + (size_t)row * HH + k0 + sc4);
    }
#pragma unroll
    for (int r = 0; r < 2; ++r) {
        const int row = srow + 32 * r;
        *(float4*)&sh[0][row * LDH + sc4] = px[r];
        *(float4*)&sw[0][row * LDH + sc4] = pw[r];
    }
    __syncthreads();

    // ---- main K loop: double-buffered, 1 barrier per chunk ----
    for (int c = 0; c < nch; ++c) {
        const int buf = c & 1;
        const bool more = (c + 1 < nch);
        if (more) {
            const int kn = k0 + (c + 1) * KC;
#pragma unroll
            for (int r = 0; r < 2; ++r) {
                const int row = srow + 32 * r;
                px[r] = *(const float4*)(x + (size_t)(tok0 + row) * HH + kn + sc4);
                pw[r] = *(const float4*)(w + (size_t)row * HH + kn + sc4);
            }
        }

#pragma unroll
        for (int kk = 0; kk < KC; kk += 4) {
            float4 ha[4], wb[4];
#pragma unroll
            for (int i = 0; i < 4; ++i)
                ha[i] = *(const float4*)&sh[buf][(ty + 16 * i) * LDH + kk];
#pragma unroll
            for (int j = 0; j < 4; ++j)
                wb[j] = *(const float4*)&sw[buf][(tx + 16 * j) * LDH + kk];
#pragma unroll
            for (int i = 0; i < 4; ++i)
#pragma unroll
                for (int j = 0; j < 4; ++j) {
                    acc[i][j] = fmaf(ha[i].x, wb[j].x, acc[i][j]);
                    acc[i][j] = fmaf(ha[i].y, wb[j].y, acc[i][j]);
                    acc[i][j] = fmaf(ha[i].z, wb[j].z, acc[i][j]);
                    acc[i][j] = fmaf(ha[i].w, wb[j].w, acc[i][j]);
                }
        }

        if (more) {
            const int nbuf = (c + 1) & 1;
#pragma unroll
            for (int r = 0; r < 2; ++r) {
                const int row = srow + 32 * r;
                *(float4*)&sh[nbuf][row * LDH + sc4] = px[r];
                *(float4*)&sw[nbuf][row * LDH + sc4] = pw[r];
            }
        }
        __syncthreads();
    }

    // ---- write partials: P[s][tok0 + ty+16i][tx+16j] ----
    float* Pw = P + ((size_t)s * NT + tok0) * EE;
#pragma unroll
    for (int i = 0; i < 4; ++i)
#pragma unroll
        for (int j = 0; j < 4; ++j)
            Pw[(ty + 16 * i) * EE + tx + 16 * j] = acc[i][j];
}

// ---------------- Kernel 2: reduce S slices + logits + top-8 softmax ----------------
// grid 256, block 256. 64 tokens/WG; 4 threads per token (16 experts each) for
// the reduction + logit store; then lane-per-token top-k (Round-1-proven code).
__global__ __launch_bounds__(256, 4) void reduce_topk(
    const float* __restrict__ P,   // [S][NT, E]
    int S,
    float* __restrict__ out_logits,
    float* __restrict__ out_wts,
    float* __restrict__ out_idx)
{
    __shared__ float slog[BT * LS];

    const int t    = threadIdx.x;
    const int tok0 = blockIdx.x * BT;
    const int tr   = t >> 2;        // token row 0..63
    const int p    = t & 3;         // expert 16-block

    float v[16];
#pragma unroll
    for (int c = 0; c < 4; ++c) {
        float4 a = *(const float4*)(P + ((size_t)(tok0 + tr)) * EE + 16 * p + 4 * c);
        v[4 * c + 0] = a.x; v[4 * c + 1] = a.y; v[4 * c + 2] = a.z; v[4 * c + 3] = a.w;
    }
    for (int s = 1; s < S; ++s) {
#pragma unroll
        for (int c = 0; c < 4; ++c) {
            float4 a = *(const float4*)(P + ((size_t)s * NT + tok0 + tr) * EE + 16 * p + 4 * c);
            v[4 * c + 0] += a.x; v[4 * c + 1] += a.y; v[4 * c + 2] += a.z; v[4 * c + 3] += a.w;
        }
    }

    // store logits + stage for top-k
#pragma unroll
    for (int c = 0; c < 4; ++c) {
        float4 a;
        a.x = v[4 * c + 0]; a.y = v[4 * c + 1]; a.z = v[4 * c + 2]; a.w = v[4 * c + 3];
        *(float4*)(out_logits + (size_t)(tok0 + tr) * EE + 16 * p + 4 * c) = a;
        *(float4*)&slog[tr * LS + 16 * p + 4 * c] = a;
    }
    __syncthreads();

    // ---- top-8 + softmax: one lane per token ----
    if (t < BT) {
        float tv[TOPK];
        int   ti[TOPK];
#pragma unroll
        for (int q = 0; q < TOPK; ++q) { tv[q] = -INFINITY; ti[q] = 0; }

        for (int e = 0; e < EE; ++e) {
            const float val = slog[t * LS + e];
            if (val > tv[TOPK - 1]) {
                tv[TOPK - 1] = val;
                ti[TOPK - 1] = e;
#pragma unroll
                for (int q = TOPK - 1; q > 0; --q) {
                    if (tv[q] > tv[q - 1]) {   // strict: lowest-index-first on ties
                        float fv = tv[q]; tv[q] = tv[q - 1]; tv[q - 1] = fv;
                        int   fi = ti[q]; ti[q] = ti[q - 1]; ti[q - 1] = fi;
                    }
                }
            }
        }

        const float m = tv[0];
        float ew[TOPK];
        float sum = 0.f;
#pragma unroll
        for (int q = 0; q < TOPK; ++q) { ew[q] = expf(tv[q] - m); sum += ew[q]; }
        const float inv = 1.f / sum;

        const size_t tok = (size_t)(tok0 + t);
        float4 w0, w1, i0, i1;
        w0.x = ew[0] * inv; w0.y = ew[1] * inv; w0.z = ew[2] * inv; w0.w = ew[3] * inv;
        w1.x = ew[4] * inv; w1.y = ew[5] * inv; w1.z = ew[6] * inv; w1.w = ew[7] * inv;
        i0.x = (float)ti[0]; i0.y = (float)ti[1]; i0.z = (float)ti[2]; i0.w = (float)ti[3];
        i1.x = (float)ti[4]; i1.y = (float)ti[5]; i1.z = (float)ti[6]; i1.w = (float)ti[7];
        *(float4*)(out_wts + tok * TOPK)     = w0;
        *(float4*)(out_wts + tok * TOPK + 4) = w1;
        *(float4*)(out_idx + tok * TOPK)     = i0;
        *(float4*)(out_idx + tok * TOPK + 4) = i1;
    }
}

extern "C" void kernel_launch(void* const* d_in, const int* in_sizes, int n_in,
                              void* d_out, int out_size, void* d_ws, size_t ws_size,
                              hipStream_t stream) {
    const float* x = (const float*)d_in[0];   // hidden_states [4,4096,2048] fp32
    const float* w = (const float*)d_in[1];   // gate_w [64,2048] fp32
    float* out        = (float*)d_out;
    float* out_logits = out;                              // 16384*64
    float* out_wts    = out + (size_t)NT * EE;            // 16384*8
    float* out_idx    = out_wts + (size_t)NT * TOPK;      // 16384*8

    const size_t sliceB = (size_t)NT * EE * sizeof(float);   // 4.2 MB per slice
    int S;
    float* P;
    if (ws_size >= 4 * sliceB)      { S = 4; P = (float*)d_ws; }
    else if (ws_size >= 2 * sliceB) { S = 2; P = (float*)d_ws; }
    else                            { S = 1; P = out_logits; }

    dim3 grid1(NT / BT, S), block(256);
    hipLaunchKernelGGL(gemm_part, grid1, block, 0, stream, x, w, P, HH / S);

    dim3 grid2(NT / BT);
    hipLaunchKernelGGL(reduce_topk, grid2, block, 0, stream,
                       P, S, out_logits, out_wts, out_idx);
}

// Round 4
// 337.380 us; speedup vs baseline: 3.6053x; 3.6053x over previous
//
#include <hip/hip_runtime.h>
#include <math.h>

// Problem constants
#define HH 2048
#define EE 64
#define TOPK 8
#define NT 16384
#define BT 64            // tokens per WG (kernel1 tile: 64 tokens x 64 experts)
#define KC 32            // K chunk
#define LDH 36           // LDS row stride (floats): +16-row-strided reads -> <=2-way banks (free)
#define LS 68            // slog row stride (floats) in kernel2

// ---------------- Kernel 1: fp32 GEMM partial over a K-range ----------------
// grid (256, S); block 256. WG (m, s): tokens m*64..+64, experts 0..64,
// K in [s*kper, (s+1)*kper). Writes partials P[s][token][expert].
// NOTE: __launch_bounds__(256, 1) — round 3 used (256,4) and the allocator
// cut VGPRs to 64 and spilled the inner-loop arrays to scratch (4.5 GB HBM
// traffic, VALUBusy 4%). (256,1) gives the ~84 VGPRs this body needs;
// occupancy is LDS-limited at 4 blocks/CU (36 KB) = 4 waves/SIMD anyway.
__global__ __launch_bounds__(256, 1) void gemm_part(
    const float* __restrict__ x,   // [NT, H]
    const float* __restrict__ w,   // [E, H]
    float* __restrict__ P,         // [S][NT, E]
    int kper)
{
    __shared__ float sh[2][BT * LDH];
    __shared__ float sw[2][BT * LDH];

    const int t  = threadIdx.x;
    const int tx = t & 15;         // expert base lane: experts tx+16j
    const int ty = t >> 4;         // token base lane:  tokens  ty+16i
    const int tok0 = blockIdx.x * BT;
    const int s    = blockIdx.y;
    const int k0   = s * kper;
    const int nch  = kper / KC;

    // staging role: thread t covers rows {t>>3, (t>>3)+32}, float4 col (t&7)*4
    const int srow = t >> 3;
    const int sc4  = (t & 7) * 4;

    float acc[4][4];
#pragma unroll
    for (int i = 0; i < 4; ++i)
#pragma unroll
        for (int j = 0; j < 4; ++j) acc[i][j] = 0.f;

    float4 px[2], pw[2];

    // ---- prologue: load chunk 0 ----
#pragma unroll
    for (int r = 0; r < 2; ++r) {
        const int row = srow + 32 * r;
        px[r] = *(const float4*)(x + (size_t)(tok0 + row) * HH + k0 + sc4);
        pw[r] = *(const float4*)(w + (size_t)row * HH + k0 + sc4);
    }
#pragma unroll
    for (int r = 0; r < 2; ++r) {
        const int row = srow + 32 * r;
        *(float4*)&sh[0][row * LDH + sc4] = px[r];
        *(float4*)&sw[0][row * LDH + sc4] = pw[r];
    }
    __syncthreads();

    // ---- main K loop: double-buffered, 1 barrier per chunk ----
    for (int c = 0; c < nch; ++c) {
        const int buf = c & 1;
        const bool more = (c + 1 < nch);
        if (more) {
            const int kn = k0 + (c + 1) * KC;
#pragma unroll
            for (int r = 0; r < 2; ++r) {
                const int row = srow + 32 * r;
                px[r] = *(const float4*)(x + (size_t)(tok0 + row) * HH + kn + sc4);
                pw[r] = *(const float4*)(w + (size_t)row * HH + kn + sc4);
            }
        }

#pragma unroll
        for (int kk = 0; kk < KC; kk += 4) {
            float4 ha[4], wb[4];
#pragma unroll
            for (int i = 0; i < 4; ++i)
                ha[i] = *(const float4*)&sh[buf][(ty + 16 * i) * LDH + kk];
#pragma unroll
            for (int j = 0; j < 4; ++j)
                wb[j] = *(const float4*)&sw[buf][(tx + 16 * j) * LDH + kk];
#pragma unroll
            for (int i = 0; i < 4; ++i)
#pragma unroll
                for (int j = 0; j < 4; ++j) {
                    acc[i][j] = fmaf(ha[i].x, wb[j].x, acc[i][j]);
                    acc[i][j] = fmaf(ha[i].y, wb[j].y, acc[i][j]);
                    acc[i][j] = fmaf(ha[i].z, wb[j].z, acc[i][j]);
                    acc[i][j] = fmaf(ha[i].w, wb[j].w, acc[i][j]);
                }
        }

        if (more) {
            const int nbuf = (c + 1) & 1;
#pragma unroll
            for (int r = 0; r < 2; ++r) {
                const int row = srow + 32 * r;
                *(float4*)&sh[nbuf][row * LDH + sc4] = px[r];
                *(float4*)&sw[nbuf][row * LDH + sc4] = pw[r];
            }
        }
        __syncthreads();
    }

    // ---- write partials: P[s][tok0 + ty+16i][tx+16j] ----
    float* Pw = P + ((size_t)s * NT + tok0) * EE;
#pragma unroll
    for (int i = 0; i < 4; ++i)
#pragma unroll
        for (int j = 0; j < 4; ++j)
            Pw[(ty + 16 * i) * EE + tx + 16 * j] = acc[i][j];
}

// ---------------- Kernel 2: reduce S slices + logits + top-8 softmax ----------------
// grid 256, block 256. 64 tokens/WG; 4 threads per token (16 experts each) for
// the reduction + logit store; then lane-per-token top-k (Round-1-proven code).
__global__ __launch_bounds__(256, 1) void reduce_topk(
    const float* __restrict__ P,   // [S][NT, E]
    int S,
    float* __restrict__ out_logits,
    float* __restrict__ out_wts,
    float* __restrict__ out_idx)
{
    __shared__ float slog[BT * LS];

    const int t    = threadIdx.x;
    const int tok0 = blockIdx.x * BT;
    const int tr   = t >> 2;        // token row 0..63
    const int p    = t & 3;         // expert 16-block

    float v[16];
#pragma unroll
    for (int c = 0; c < 4; ++c) {
        float4 a = *(const float4*)(P + ((size_t)(tok0 + tr)) * EE + 16 * p + 4 * c);
        v[4 * c + 0] = a.x; v[4 * c + 1] = a.y; v[4 * c + 2] = a.z; v[4 * c + 3] = a.w;
    }
    for (int s = 1; s < S; ++s) {
#pragma unroll
        for (int c = 0; c < 4; ++c) {
            float4 a = *(const float4*)(P + ((size_t)s * NT + tok0 + tr) * EE + 16 * p + 4 * c);
            v[4 * c + 0] += a.x; v[4 * c + 1] += a.y; v[4 * c + 2] += a.z; v[4 * c + 3] += a.w;
        }
    }

    // store logits + stage for top-k
#pragma unroll
    for (int c = 0; c < 4; ++c) {
        float4 a;
        a.x = v[4 * c + 0]; a.y = v[4 * c + 1]; a.z = v[4 * c + 2]; a.w = v[4 * c + 3];
        *(float4*)(out_logits + (size_t)(tok0 + tr) * EE + 16 * p + 4 * c) = a;
        *(float4*)&slog[tr * LS + 16 * p + 4 * c] = a;
    }
    __syncthreads();

    // ---- top-8 + softmax: one lane per token ----
    if (t < BT) {
        float tv[TOPK];
        int   ti[TOPK];
#pragma unroll
        for (int q = 0; q < TOPK; ++q) { tv[q] = -INFINITY; ti[q] = 0; }

        for (int e = 0; e < EE; ++e) {
            const float val = slog[t * LS + e];
            if (val > tv[TOPK - 1]) {
                tv[TOPK - 1] = val;
                ti[TOPK - 1] = e;
#pragma unroll
                for (int q = TOPK - 1; q > 0; --q) {
                    if (tv[q] > tv[q - 1]) {   // strict: lowest-index-first on ties
                        float fv = tv[q]; tv[q] = tv[q - 1]; tv[q - 1] = fv;
                        int   fi = ti[q]; ti[q] = ti[q - 1]; ti[q - 1] = fi;
                    }
                }
            }
        }

        const float m = tv[0];
        float ew[TOPK];
        float sum = 0.f;
#pragma unroll
        for (int q = 0; q < TOPK; ++q) { ew[q] = expf(tv[q] - m); sum += ew[q]; }
        const float inv = 1.f / sum;

        const size_t tok = (size_t)(tok0 + t);
        float4 w0, w1, i0, i1;
        w0.x = ew[0] * inv; w0.y = ew[1] * inv; w0.z = ew[2] * inv; w0.w = ew[3] * inv;
        w1.x = ew[4] * inv; w1.y = ew[5] * inv; w1.z = ew[6] * inv; w1.w = ew[7] * inv;
        i0.x = (float)ti[0]; i0.y = (float)ti[1]; i0.z = (float)ti[2]; i0.w = (float)ti[3];
        i1.x = (float)ti[4]; i1.y = (float)ti[5]; i1.z = (float)ti[6]; i1.w = (float)ti[7];
        *(float4*)(out_wts + tok * TOPK)     = w0;
        *(float4*)(out_wts + tok * TOPK + 4) = w1;
        *(float4*)(out_idx + tok * TOPK)     = i0;
        *(float4*)(out_idx + tok * TOPK + 4) = i1;
    }
}

extern "C" void kernel_launch(void* const* d_in, const int* in_sizes, int n_in,
                              void* d_out, int out_size, void* d_ws, size_t ws_size,
                              hipStream_t stream) {
    const float* x = (const float*)d_in[0];   // hidden_states [4,4096,2048] fp32
    const float* w = (const float*)d_in[1];   // gate_w [64,2048] fp32
    float* out        = (float*)d_out;
    float* out_logits = out;                              // 16384*64
    float* out_wts    = out + (size_t)NT * EE;            // 16384*8
    float* out_idx    = out_wts + (size_t)NT * TOPK;      // 16384*8

    const size_t sliceB = (size_t)NT * EE * sizeof(float);   // 4.2 MB per slice
    int S;
    float* P;
    if (ws_size >= 4 * sliceB)      { S = 4; P = (float*)d_ws; }
    else if (ws_size >= 2 * sliceB) { S = 2; P = (float*)d_ws; }
    else                            { S = 1; P = out_logits; }

    dim3 grid1(NT / BT, S), block(256);
    hipLaunchKernelGGL(gemm_part, grid1, block, 0, stream, x, w, P, HH / S);

    dim3 grid2(NT / BT);
    hipLaunchKernelGGL(reduce_topk, grid2, block, 0, stream,
                       P, S, out_logits, out_wts, out_idx);
}